// Round 13
// baseline (447.980 us; speedup 1.0000x reference)
//
#include <hip/hip_runtime.h>

#define GX 432
#define GY 496
#define G_TOTAL (GX * GY) /* 214272 = 837*256 exactly, GZ=1 */
#define MAX_PTS 32
#define MAX_VOX 20000
#define CAP 64
#define INF_SENTINEL 0x7F7F7F7F
#define PREFIX_K 65536  /* ~33k in-range claims -> ~31k distinct cells >= 20000 */
#define NB_FIN 837      /* finalize grid; co-resident (see launch_bounds note) */

typedef unsigned long long u64;

// IEEE float32 ops exactly matching the reference:
// c = floor((p - lo)/vs), lo = [0, -39.68, -3], vs = [.16,.16,4].
__device__ __forceinline__ int cell_of(float4 p, bool& ok) {
    float fx = floorf((p.x - 0.0f) / 0.16f);
    float fy = floorf((p.y + 39.68f) / 0.16f);
    float fz = floorf((p.z + 3.0f) / 4.0f);
    int cx = (int)fx, cy = (int)fy, cz = (int)fz;
    ok = (cx >= 0 && cx < GX && cy >= 0 && cy < GY && cz == 0);
    return cy * GX + cx;
}

// Pass 1: 1 point/thread stream + prefix claims (non-returning atomicMin —
// consuming the return value costs a per-wave ~900cy drain, R10 lesson).
// Fused inits: bits[] zero, ctrl[] (barrier counters + dcount) zero.
__global__ __launch_bounds__(256) void pass1(const float4* __restrict__ pts,
                                             int* __restrict__ lin,
                                             int* __restrict__ first,
                                             u64* __restrict__ bits,
                                             int* __restrict__ ctrl,
                                             int W, int K, int n) {
    int i = blockIdx.x * 256 + threadIdx.x;
    if (i < W) bits[i] = 0ull;
    if (i < 256) ctrl[i] = 0;
    if (i >= n) return;
    float4 p = pts[i];
    bool ok;
    int c = cell_of(p, ok);
    lin[i] = ok ? c : -1;
    if (ok && i < K) atomicMin(&first[c], i);  // fire-and-forget
}

// Grid-wide barrier: valid ONLY because all NB_FIN blocks are co-resident
// (837 blocks * 4 waves = 3348 waves << 8192 device capacity; launch_bounds
// (256,4) caps VGPR<=128 so 4 blocks/CU always fit). threadfence publishes
// this block's normal stores before the ticket; acquire spin orders reads.
__device__ __forceinline__ void gridBarrier(int* ctr, int nb) {
    __syncthreads();
    if (threadIdx.x == 0) {
        __threadfence();
        __hip_atomic_fetch_add(ctr, 1, __ATOMIC_RELEASE,
                               __HIP_MEMORY_SCOPE_AGENT);
        while (__hip_atomic_load(ctr, __ATOMIC_ACQUIRE,
                                 __HIP_MEMORY_SCOPE_AGENT) < nb)
            __builtin_amdgcn_s_sleep(2);
    }
    __syncthreads();
}

// Finalize: countD -> guard -> markFirst -> word-prefix -> rank, one kernel.
// Cross-phase data (bits, wordLocal, sums, dcount, guarded first) is read
// with AGENT-scope atomic loads: normal loads can hit stale clean L2 lines
// (incl. harness 0xAA poison) since device atomics update memory-side only.
__global__ __launch_bounds__(256, 4) void finalize(
    const float4* __restrict__ pts, int* first, u64* bits,
    unsigned* wordLocal, int* sums, int* ctrl, int* rank, int* cellOfRank,
    int* vcount, float* nvOut, int W, int nbW, int K, int n) {
    int t = threadIdx.x, b = blockIdx.x;
    int c = b * 256 + t;  // cell domain: NB_FIN*256 == G_TOTAL exactly
    int lane = t & 63, w = t >> 6;
    __shared__ int wsumS[4], wexcS[4];
    __shared__ int sExcl[128];
    int* dcount = &ctrl[160];

    // ---- phase 1: count distinct prefix-claimed cells + small inits ----
    if (c < MAX_VOX) { vcount[c] = -1; cellOfRank[c] = -1; }
    int have = (c < G_TOTAL && first[c] != INF_SENTINEL) ? 1 : 0;
    for (int d = 32; d >= 1; d >>= 1) have += __shfl_down(have, d, 64);
    if (lane == 0) wsumS[w] = have;
    __syncthreads();
    if (t == 0) atomicAdd(dcount, wsumS[0] + wsumS[1] + wsumS[2] + wsumS[3]);
    gridBarrier(&ctrl[0], NB_FIN);

    // ---- phase 2: guard (exact fallback; no-op for this distribution) ----
    bool need = __hip_atomic_load(dcount, __ATOMIC_RELAXED,
                                  __HIP_MEMORY_SCOPE_AGENT) < MAX_VOX;
    if (need) {
        for (int i = K + b * 256 + t; i < n; i += NB_FIN * 256) {
            float4 p = pts[i];
            bool ok;
            int cc = cell_of(p, ok);
            if (ok) {
                int cur = __hip_atomic_load(&first[cc], __ATOMIC_RELAXED,
                                            __HIP_MEMORY_SCOPE_AGENT);
                if (cur > i) atomicMin(&first[cc], i);
            }
        }
    }
    gridBarrier(&ctrl[32], NB_FIN);

    // ---- phase 3: mark first-point bits ----
    int f = INF_SENTINEL;
    if (c < G_TOTAL) {
        f = need ? __hip_atomic_load(&first[c], __ATOMIC_RELAXED,
                                     __HIP_MEMORY_SCOPE_AGENT)
                 : first[c];
        if (f >= 0 && f < n) atomicOr(&bits[f >> 6], 1ull << (f & 63));
    }
    gridBarrier(&ctrl[64], NB_FIN);

    // ---- phase 4: per-word exclusive prefix within 256-word groups ----
    if (b < nbW) {
        int wi = b * 256 + t;
        u64 mask = (wi < W)
            ? __hip_atomic_load(&bits[wi], __ATOMIC_RELAXED,
                                __HIP_MEMORY_SCOPE_AGENT)
            : 0ull;
        int v = __popcll(mask);
        int x = v;
        for (int d = 1; d < 64; d <<= 1) {
            int y = __shfl_up(x, d, 64);
            if (lane >= d) x += y;
        }
        if (lane == 63) wsumS[w] = x;
        __syncthreads();
        if (t == 0) {
            int a = 0;
            for (int j = 0; j < 4; j++) { wexcS[j] = a; a += wsumS[j]; }
            sums[b] = a;
        }
        __syncthreads();
        if (wi < W) wordLocal[wi] = (unsigned)(wexcS[w] + x - v);
    }
    gridBarrier(&ctrl[96], NB_FIN);

    // ---- phase 4b: every block redundantly scans sums[0..nbW) into LDS ----
    int sv = (t < nbW) ? __hip_atomic_load(&sums[t], __ATOMIC_RELAXED,
                                           __HIP_MEMORY_SCOPE_AGENT)
                       : 0;
    int sx = sv;
    for (int d = 1; d < 64; d <<= 1) {
        int y = __shfl_up(sx, d, 64);
        if (lane >= d) sx += y;
    }
    if (lane == 63) wsumS[w] = sx;
    __syncthreads();
    if (t == 0) {
        int a = 0;
        for (int j = 0; j < 4; j++) { wexcS[j] = a; a += wsumS[j]; }
        if (b == 0) nvOut[0] = (float)(a < MAX_VOX ? a : MAX_VOX);
    }
    __syncthreads();
    if (t < 128) sExcl[t] = wexcS[w] + sx - sv;
    __syncthreads();

    // ---- phase 5: rank every cell (INF when unclaimed) ----
    if (c < G_TOTAL) {
        if (f < 0 || f >= n) {
            rank[c] = INF_SENTINEL;
        } else {
            int wf = f >> 6, bb = f & 63;
            u64 m = __hip_atomic_load(&bits[wf], __ATOMIC_RELAXED,
                                      __HIP_MEMORY_SCOPE_AGENT);
            unsigned wl = __hip_atomic_load(&wordLocal[wf], __ATOMIC_RELAXED,
                                            __HIP_MEMORY_SCOPE_AGENT);
            u64 lowmask = (bb == 0) ? 0ull : ((~0ull) >> (64 - bb));
            int vr = sExcl[wf >> 8] + (int)wl + __popcll(m & lowmask);
            rank[c] = vr;
            if (vr < MAX_VOX) cellOfRank[vr] = c;
        }
    }
}

// Pass 5: 1 point/thread. Append point indices into kept voxels' lists.
// vcount starts at -1; atomicAdd return IS the slot ticket (only ~95k reach).
__global__ __launch_bounds__(256) void pass5(const int* __restrict__ lin,
                                             const int* __restrict__ rank,
                                             int* __restrict__ vcount,
                                             int* __restrict__ list, int n) {
    int i = blockIdx.x * 256 + threadIdx.x;
    if (i >= n) return;
    int c = lin[i];
    if (c < 0) return;
    int vr = rank[c];
    if (vr >= MAX_VOX) return;
    int pos = atomicAdd(&vcount[vr], 1) + 1;
    if (pos < CAP) list[vr * CAP + pos] = i;
}

// Pass F: 4 voxels per 256-thread block (one wave each). Counting-sort the
// collected indices (LDS broadcast reads), write all 32 slots + num_points
// + coors (so no d_out pre-memset is needed).
__global__ __launch_bounds__(256) void passF(const float4* __restrict__ pts,
                                             const int* __restrict__ vcount,
                                             const int* __restrict__ cellOfRank,
                                             const int* __restrict__ list,
                                             float4* __restrict__ voxOut,
                                             float* __restrict__ coorsOut,
                                             float* __restrict__ npOut) {
    __shared__ int s[4][CAP];
    __shared__ int slotPt[4][MAX_PTS];
    int w = threadIdx.x >> 6, lane = threadIdx.x & 63;
    int v = blockIdx.x * 4 + w;
    int cnt = vcount[v] + 1;
    int m = cnt < CAP ? cnt : CAP;
    s[w][lane] = (lane < m) ? list[v * CAP + lane] : 0x7FFFFFFF;
    if (lane < MAX_PTS) slotPt[w][lane] = -1;
    __syncthreads();
    int my = s[w][lane];
    int r = 0;
#pragma unroll
    for (int j = 0; j < CAP; j++) r += (s[w][j] < my) ? 1 : 0;  // broadcast
    if (lane < m && r < MAX_PTS) slotPt[w][r] = my;
    __syncthreads();
    if (lane < MAX_PTS) {
        int p = slotPt[w][lane];
        float4 val = make_float4(0.f, 0.f, 0.f, 0.f);
        if (p >= 0) val = pts[p];
        voxOut[(size_t)v * MAX_PTS + lane] = val;
    }
    if (lane == 0) {
        npOut[v] = (float)(cnt < MAX_PTS ? cnt : MAX_PTS);
        int cell = cellOfRank[v];
        if (cell < 0) {
            coorsOut[3 * v + 0] = -1.0f;
            coorsOut[3 * v + 1] = -1.0f;
            coorsOut[3 * v + 2] = -1.0f;
        } else {
            coorsOut[3 * v + 0] = 0.0f;  // cz (GZ==1)
            coorsOut[3 * v + 1] = (float)(cell / GX);
            coorsOut[3 * v + 2] = (float)(cell % GX);
        }
    }
}

extern "C" void kernel_launch(void* const* d_in, const int* in_sizes, int n_in,
                              void* d_out, int out_size, void* d_ws, size_t ws_size,
                              hipStream_t stream) {
    const float4* pts = (const float4*)d_in[0];
    int n = in_sizes[0] / 4;  // 2,000,000
    int W = (n + 63) >> 6;    // 31250 bitmap words
    int K = PREFIX_K < n ? PREFIX_K : n;

    char* ws = (char*)d_ws;
    size_t off = 0;
    auto alloc = [&](size_t bytes) -> void* {
        void* p = (void*)(ws + off);
        off = (off + bytes + 255) & ~(size_t)255;
        return p;
    };
    int* first = (int*)alloc((size_t)G_TOTAL * 4);
    int* ctrl = (int*)alloc(256 * 4);  // barrier counters @0,32,64,96; dcount @160
    int* lin = (int*)alloc((size_t)n * 4);
    u64* bits = (u64*)alloc((size_t)W * 8);
    unsigned* wordLocal = (unsigned*)alloc((size_t)W * 4);
    int* sums = (int*)alloc(128 * 4);
    int* rank = (int*)alloc((size_t)G_TOTAL * 4);
    int* vcount = (int*)alloc((size_t)MAX_VOX * 4);
    int* cellOfRank = (int*)alloc((size_t)MAX_VOX * 4);
    int* list = (int*)alloc((size_t)MAX_VOX * CAP * 4);
    (void)ws_size;
    (void)n_in;
    (void)out_size;

    float* out = (float*)d_out;
    float4* voxOut = (float4*)out;                          // 20000*32*4
    float* coorsOut = out + (size_t)MAX_VOX * MAX_PTS * 4;  // 20000*3
    float* npOut = coorsOut + (size_t)MAX_VOX * 3;          // 20000
    float* nvOut = npOut + MAX_VOX;                         // 1

    hipMemsetAsync(first, 0x7F, (size_t)G_TOTAL * 4, stream);  // INF

    int nbP = (n + 255) / 256;  // 7813
    int nbW = (W + 255) / 256;  // 123

    pass1<<<nbP, 256, 0, stream>>>(pts, lin, first, bits, ctrl, W, K, n);
    finalize<<<NB_FIN, 256, 0, stream>>>(pts, first, bits, wordLocal, sums,
                                         ctrl, rank, cellOfRank, vcount,
                                         nvOut, W, nbW, K, n);
    pass5<<<nbP, 256, 0, stream>>>(lin, rank, vcount, list, n);
    passF<<<MAX_VOX / 4, 256, 0, stream>>>(pts, vcount, cellOfRank, list,
                                           voxOut, coorsOut, npOut);
}